// Round 1
// 360.008 us; speedup vs baseline: 1.1619x; 1.1619x over previous
//
#include <hip/hip_runtime.h>

// MHA forward. f32 in/out; bf16 MFMA compute (16x16x32), fp32 accum.
// Pipeline: cvt_x + transposeW -> merged QKV GEMM (all coalesced writes)
//           -> transpose_v -> flash attention (swapped-operand MFMA, lane-local
//           softmax, dbuf gll16 K/V, 1 barrier/iter) -> out GEMM.
// Workspace (u16): WqT,WkT,WvT(contig Bt),WoT (1M ea), xb(8M; ->Vtb),
// Qb, Kb, Vb(8M; ->Ctx) = 72 MB.
//
// R10 vs R9 (attn only): (1) swapped-operand QK^T (mfma(K,Q)) and PV
// (mfma(Vt,P)) put q on the MFMA column axis -> each lane owns ONE q-row;
// softmax max/sum are in-lane + 2 shfl_xor; alpha/m/l once per lane
// (lane-parallel) instead of 4x serial DPP chains. (2) P packed with
// v_cvt_pk_bf16_f32 (8 ops) + 8 ds_write_b32 instead of 16 f2bf + 16 b16
// writes. (3) exp2-domain softmax (scores pre-scaled by 0.125*log2e).
// (4) P stride 68->64 w/ chunk-XOR swizzle: LDS 41472->40960 B = exactly
// 4 blocks/CU (was 3).

typedef unsigned short u16;
typedef __attribute__((ext_vector_type(8))) short short8;   // 8 bf16
typedef __attribute__((ext_vector_type(4))) float floatx4;  // 4 fp32
typedef __attribute__((ext_vector_type(2))) unsigned int uint2v;

#define NEG_BIG (-1e30f)
#define SCL_LOG2E 0.1803368801111244f  // (1/sqrt(64)) * log2(e)

__device__ __forceinline__ u16 f2bf(float f) {
  unsigned int u = __builtin_bit_cast(unsigned int, f);
  u += 0x7fffu + ((u >> 16) & 1u);
  return (u16)(u >> 16);
}

__device__ __forceinline__ short8 cvt8(const float* __restrict__ p) {
  const floatx4 a = *(const floatx4*)p;
  const floatx4 b = *(const floatx4*)(p + 4);
  short8 r;
  r[0] = (short)f2bf(a[0]); r[1] = (short)f2bf(a[1]);
  r[2] = (short)f2bf(a[2]); r[3] = (short)f2bf(a[3]);
  r[4] = (short)f2bf(b[0]); r[5] = (short)f2bf(b[1]);
  r[6] = (short)f2bf(b[2]); r[7] = (short)f2bf(b[3]);
  return r;
}

// async global->LDS, 16B/lane; LDS dest = wave-uniform base + lane*16 [m97]
__device__ __forceinline__ void gll16(const u16* g, u16* l) {
  __builtin_amdgcn_global_load_lds((const __attribute__((address_space(1))) void*)g,
                                   (__attribute__((address_space(3))) void*)l,
                                   16, 0, 0);
}

// ---------------------------------------------------------------------------
__global__ void cvt_x(const float* __restrict__ x, u16* __restrict__ xb) {
  const int i = blockIdx.x * 256 + threadIdx.x;  // 8 elems each
  *(short8*)(xb + (size_t)i * 8) = cvt8(x + (size_t)i * 8);
}

// ---------------------------------------------------------------------------
// 1024x1024 transpose + f32->bf16 (x4 matrices via grid.z).
__global__ void transpose4(const float* __restrict__ s0, const float* __restrict__ s1,
                           const float* __restrict__ s2, const float* __restrict__ s3,
                           u16* __restrict__ d0, u16* __restrict__ d1,
                           u16* __restrict__ d2, u16* __restrict__ d3) {
  __shared__ u16 tile[64][72];
  const float* src; u16* dst;
  switch (blockIdx.z) {
    case 0: src = s0; dst = d0; break;
    case 1: src = s1; dst = d1; break;
    case 2: src = s2; dst = d2; break;
    default: src = s3; dst = d3; break;
  }
  const int t = threadIdx.x;
  const int c = t & 63, rg = t >> 6;
  const int x0 = blockIdx.x * 64, y0 = blockIdx.y * 64;
#pragma unroll
  for (int i = 0; i < 16; ++i) {
    const int row = rg * 16 + i;
    tile[row][c] = f2bf(src[(size_t)(y0 + row) * 1024 + x0 + c]);
  }
  __syncthreads();
#pragma unroll
  for (int i = 0; i < 16; ++i) {
    const int row = rg * 16 + i;
    dst[(size_t)(x0 + row) * 1024 + y0 + c] = tile[c][row];
  }
}

// ---------------------------------------------------------------------------
// Per-head V transpose: Vb [b,h,l,dh] -> Vt [b,h,dh,l]. Coalesced both sides.
__global__ void transpose_v(const u16* __restrict__ Vb, u16* __restrict__ Vt) {
  __shared__ u16 tile[64][66];  // stride 66: column reads 2-way only
  const int bh = blockIdx.y;
  const int l0 = blockIdx.x * 64;
  const size_t base = (size_t)bh * (2048 * 64);
  const int t = threadIdx.x;
#pragma unroll
  for (int c = t; c < 512; c += 256) {
    const int row = c >> 3, cc = c & 7;
    *(short8*)&tile[row][cc * 8] =
        *(const short8*)(Vb + base + (size_t)(l0 + row) * 64 + cc * 8);
  }
  __syncthreads();
  const int c2 = t & 63, rg = t >> 6;
#pragma unroll
  for (int i = 0; i < 16; ++i) {
    const int dr = rg * 16 + i;
    Vt[base + (size_t)dr * 2048 + l0 + c2] = tile[c2][dr];
  }
}

// ---------------------------------------------------------------------------
// Merged QKV GEMM: A[8192,1024] bf16 @ Bt[3072,1024]^T (WqT|WkT|WvT) + bias.
// 128x128 tile, BK=32, m97 gll staging. All segs write [b,h,l,dh] (coalesced).
__global__ __launch_bounds__(256, 2) void gemm_qkv(
    const u16* __restrict__ A, const u16* __restrict__ Bt,
    const float* __restrict__ bq, const float* __restrict__ bk,
    const float* __restrict__ bv,
    u16* __restrict__ Qb, u16* __restrict__ Kb, u16* __restrict__ Vb) {
  const int K = 1024;
  __shared__ __align__(16) u16 As[128 * 32];
  __shared__ __align__(16) u16 Bs[128 * 32];
  const int t = threadIdx.x;
  const int w = t >> 6, l = t & 63;
  const int quad = l >> 4, l16 = l & 15;
  const int m0 = blockIdx.y * 128, n0 = blockIdx.x * 128;
  const int wr = w >> 1, wc = w & 1;

  floatx4 acc[4][4] = {};

  for (int k0 = 0; k0 < K; k0 += 32) {
    __syncthreads();
#pragma unroll
    for (int p = 0; p < 2; ++p) {
      const int c0 = (p * 4 + w) * 64;
      const int c = c0 + l;
      const int row = c >> 2;
      const int koff = (c & 3) * 8;
      gll16(A + (size_t)(m0 + row) * K + k0 + koff, &As[c0 * 8]);
      gll16(Bt + (size_t)(n0 + row) * K + k0 + koff, &Bs[c0 * 8]);
    }
    __syncthreads();

    short8 af[4], bf[4];
#pragma unroll
    for (int i = 0; i < 4; ++i)
      af[i] = *(const short8*)&As[(wr * 64 + i * 16 + l16) * 32 + quad * 8];
#pragma unroll
    for (int j = 0; j < 4; ++j)
      bf[j] = *(const short8*)&Bs[(wc * 64 + j * 16 + l16) * 32 + quad * 8];
#pragma unroll
    for (int i = 0; i < 4; ++i)
#pragma unroll
      for (int j = 0; j < 4; ++j)
        acc[i][j] = __builtin_amdgcn_mfma_f32_16x16x32_bf16(af[i], bf[j], acc[i][j], 0, 0, 0);
  }

  const int seg = n0 >> 10;  // 0=Q 1=K 2=V
  const float* bias = (seg == 0) ? bq : (seg == 1) ? bk : bv;
  u16* dst = (seg == 0) ? Qb : (seg == 1) ? Kb : Vb;
#pragma unroll
  for (int j = 0; j < 4; ++j) {
    const int nn = (n0 & 1023) + wc * 64 + j * 16 + l16;
    const float bvs = bias[nn];
    const int h = nn >> 6, dh = nn & 63;
#pragma unroll
    for (int i = 0; i < 4; ++i) {
      const int rb = m0 + wr * 64 + i * 16 + quad * 4;
#pragma unroll
      for (int r = 0; r < 4; ++r) {
        const int m = rb + r;
        const int b = m >> 11, ll = m & 2047;
        dst[((size_t)(b * 16 + h) * 2048 + ll) * 64 + dh] = f2bf(acc[i][j][r] + bvs);
      }
    }
  }
}

// ---------------------------------------------------------------------------
// Out GEMM: C[M,N] f32 = A[M,K] bf16 @ Bt[N,K]^T + bias[N].
__global__ __launch_bounds__(256, 2) void gemm_out(
    const u16* __restrict__ A, const u16* __restrict__ Bt,
    const float* __restrict__ bias, float* __restrict__ C, int M, int N, int K) {
  __shared__ __align__(16) u16 As[128 * 32];
  __shared__ __align__(16) u16 Bs[128 * 32];
  const int t = threadIdx.x;
  const int w = t >> 6, l = t & 63;
  const int quad = l >> 4, l16 = l & 15;
  const int m0 = blockIdx.y * 128, n0 = blockIdx.x * 128;
  const int wr = w >> 1, wc = w & 1;

  floatx4 acc[4][4] = {};

  for (int k0 = 0; k0 < K; k0 += 32) {
    __syncthreads();
#pragma unroll
    for (int p = 0; p < 2; ++p) {
      const int c0 = (p * 4 + w) * 64;
      const int c = c0 + l;
      const int row = c >> 2;
      const int koff = (c & 3) * 8;
      gll16(A + (size_t)(m0 + row) * K + k0 + koff, &As[c0 * 8]);
      gll16(Bt + (size_t)(n0 + row) * K + k0 + koff, &Bs[c0 * 8]);
    }
    __syncthreads();

    short8 af[4], bf[4];
#pragma unroll
    for (int i = 0; i < 4; ++i)
      af[i] = *(const short8*)&As[(wr * 64 + i * 16 + l16) * 32 + quad * 8];
#pragma unroll
    for (int j = 0; j < 4; ++j)
      bf[j] = *(const short8*)&Bs[(wc * 64 + j * 16 + l16) * 32 + quad * 8];
#pragma unroll
    for (int i = 0; i < 4; ++i)
#pragma unroll
      for (int j = 0; j < 4; ++j)
        acc[i][j] = __builtin_amdgcn_mfma_f32_16x16x32_bf16(af[i], bf[j], acc[i][j], 0, 0, 0);
  }

#pragma unroll
  for (int j = 0; j < 4; ++j) {
    const int n = n0 + wc * 64 + j * 16 + l16;
    const float bvs = bias[n];
#pragma unroll
    for (int i = 0; i < 4; ++i) {
      const int rb = m0 + wr * 64 + i * 16 + quad * 4;
#pragma unroll
      for (int r = 0; r < 4; ++r)
        C[(size_t)(rb + r) * N + n] = acc[i][j][r] + bvs;
    }
  }
}

// ---------------------------------------------------------------------------
// Flash attention, causal. Block = (qt, bh); 4 waves x 16 q-rows, Q in regs.
// K/V 64x64 tiles double-buffered in LDS via gll16 with chunk-XOR swizzle
// (stride 64, conflict-free b128 reads). ONE __syncthreads per k-tile.
//
// Swapped-operand MFMA: s = mfma(K_frag, Q_frag) -> S^T: lane(quad,l16) holds
// S[k = tn*16+quad*4+r][q = l16]. Each lane owns ONE q-row: softmax max/sum
// are in-lane (15 ops) + shfl_xor(16)/shfl_xor(32) across quads; alpha/m/l
// computed once per lane. PV is o = mfma(Vt_frag, P_frag) -> O^T: lane holds
// O[q=l16][d = td*16+quad*4+r]; alpha rescale stays lane-local.
// P packed to bf16 pairs via v_cvt_pk_bf16_f32 (adjacent k per lane) and
// stored 8x ds_write_b32 into wave-private LDS (stride 64, chunk-XOR swizzle;
// banks verified <=2-way on write and read). LDS total 40960 B = 4 blocks/CU.
__global__ __launch_bounds__(256, 4) void attn_kernel(
    const u16* __restrict__ Q, const u16* __restrict__ K,
    const u16* __restrict__ Vt, u16* __restrict__ ctx) {
  __shared__ __align__(16) u16 Ks[2][64 * 64];
  __shared__ __align__(16) u16 Vs[2][64 * 64];
  __shared__ __align__(16) u16 Ps[4 * 16 * 64];

  const int t = threadIdx.x;
  const int w = t >> 6, l = t & 63;
  const int quad = l >> 4, l16 = l & 15;
  const int qt = gridDim.x - 1 - blockIdx.x;  // heavy tiles first
  const int bh = blockIdx.y;
  const int q0 = qt * 64;
  const int nkt = qt + 1;
  const size_t base = (size_t)bh * (2048 * 64);
  u16* Pw = &Ps[w * 16 * 64];
  unsigned int* Pw32 = (unsigned int*)Pw;

  // staging geometry: phys chunk pc = (p*4+w)*64 + l; logical row r = pc>>3,
  // chunk cl = (pc&7) ^ (r&7). gll16 dest = chunk-contiguous (lane*16).
  const int pc0 = w * 64 + l, pc1 = (4 + w) * 64 + l;
  const int sr0 = pc0 >> 3, sc0 = (pc0 & 7) ^ (sr0 & 7);
  const int sr1 = pc1 >> 3, sc1 = (pc1 & 7) ^ (sr1 & 7);

  // Q fragments (lane's l16 = q-row): row = q0+w*16+l16, k = ks*32+quad*8
  short8 aq[2];
#pragma unroll
  for (int ks = 0; ks < 2; ++ks)
    aq[ks] = *(const short8*)(Q + base + (size_t)(q0 + w * 16 + l16) * 64 + ks * 32 + quad * 8);

  // prefetch tile 0 into buf 0
  {
    u16* kb = &Ks[0][(w * 64) * 8];   // wave-uniform base (chunk p=0 slot)
    u16* kb1 = &Ks[0][((4 + w) * 64) * 8];
    gll16(K + base + (size_t)sr0 * 64 + sc0 * 8, kb);
    gll16(K + base + (size_t)sr1 * 64 + sc1 * 8, kb1);
    u16* vb = &Vs[0][(w * 64) * 8];
    u16* vb1 = &Vs[0][((4 + w) * 64) * 8];
    gll16(Vt + base + (size_t)sr0 * 2048 + sc0 * 8, vb);
    gll16(Vt + base + (size_t)sr1 * 2048 + sc1 * 8, vb1);
  }

  floatx4 o[4] = {};
  float mrun = NEG_BIG, lsum = 0.f;

  const int swz = (l16 & 7);  // fragment-read chunk swizzle

  for (int kt = 0; kt < nkt; ++kt) {
    const int cur = kt & 1, nxt = cur ^ 1;
    __syncthreads();  // drains gll16s for buf[cur]; protects buf[nxt] reads
    if (kt + 1 < nkt) {
      const int kn = (kt + 1) * 64;
      gll16(K + base + (size_t)(kn + sr0) * 64 + sc0 * 8, &Ks[nxt][(w * 64) * 8]);
      gll16(K + base + (size_t)(kn + sr1) * 64 + sc1 * 8, &Ks[nxt][((4 + w) * 64) * 8]);
      gll16(Vt + base + (size_t)sr0 * 2048 + kn + sc0 * 8, &Vs[nxt][(w * 64) * 8]);
      gll16(Vt + base + (size_t)sr1 * 2048 + kn + sc1 * 8, &Vs[nxt][((4 + w) * 64) * 8]);
    }

    // S^T = K Q^T : 8 MFMA (swapped operands); K frag row tn*16+l16
    floatx4 s[4] = {};
#pragma unroll
    for (int ks = 0; ks < 2; ++ks)
#pragma unroll
      for (int tn = 0; tn < 4; ++tn) {
        const short8 bk = *(const short8*)&Ks[cur][(tn * 16 + l16) * 64 + (((ks * 4 + quad) ^ swz) << 3)];
        s[tn] = __builtin_amdgcn_mfma_f32_16x16x32_bf16(bk, aq[ks], s[tn], 0, 0, 0);
      }

    // scale to log2 domain + causal mask (diag tile only) + in-lane max.
    // lane's k = tn*16 + quad*4 + r; lane's q (in-block) = w*16 + l16.
    const bool diag = (kt == nkt - 1);
    float mx = NEG_BIG;
#pragma unroll
    for (int tn = 0; tn < 4; ++tn)
#pragma unroll
      for (int r = 0; r < 4; ++r) {
        float v = s[tn][r] * SCL_LOG2E;
        if (diag && (tn * 16 + quad * 4 + r > w * 16 + l16)) v = NEG_BIG;
        s[tn][r] = v;
        mx = fmaxf(mx, v);
      }
    // cross-quad (same q lives in lanes l16, l16+16, l16+32, l16+48)
    mx = fmaxf(mx, __shfl_xor(mx, 16));
    mx = fmaxf(mx, __shfl_xor(mx, 32));

    const float mnew = fmaxf(mrun, mx);
    const float alpha = exp2f(mrun - mnew);
    mrun = mnew;
    float rs = 0.f;
#pragma unroll
    for (int tn = 0; tn < 4; ++tn)
#pragma unroll
      for (int r = 0; r < 4; ++r) {
        const float p = exp2f(s[tn][r] - mnew);
        s[tn][r] = p;
        rs += p;
      }
    rs += __shfl_xor(rs, 16);
    rs += __shfl_xor(rs, 32);
    lsum = lsum * alpha + rs;
#pragma unroll
    for (int td = 0; td < 4; ++td)
#pragma unroll
      for (int r = 0; r < 4; ++r) o[td][r] *= alpha;

    // P: pack k-pairs (r even/odd adjacent in k) -> u32, wave-private LDS.
    // u32 col k2 = 8*tn + 2*quad + p; chunk swizzle cc = (k2>>2) ^ (l16&7).
#pragma unroll
    for (int tn = 0; tn < 4; ++tn)
#pragma unroll
      for (int p = 0; p < 2; ++p) {
        unsigned int pk;
        asm("v_cvt_pk_bf16_f32 %0, %1, %2"
            : "=v"(pk) : "v"(s[tn][2 * p]), "v"(s[tn][2 * p + 1]));
        const int k2 = 8 * tn + 2 * quad + p;
        const int cc = (k2 >> 2) ^ (l16 & 7);
        Pw32[l16 * 32 + cc * 4 + (k2 & 3)] = pk;
      }
    __asm__ volatile("s_waitcnt lgkmcnt(0)" ::: "memory");
    __builtin_amdgcn_wave_barrier();

    // P fragment (B-operand): row l16 = q, k = ks*32+quad*8..+7 (de-swizzle)
    short8 ap[2];
#pragma unroll
    for (int ks = 0; ks < 2; ++ks)
      ap[ks] = *(const short8*)&Pw[l16 * 64 + (((ks * 4 + quad) ^ swz) << 3)];

    // O^T += V^T P^T : 8 MFMA (swapped); Vt frag row td*16+l16 (=dh)
#pragma unroll
    for (int ks = 0; ks < 2; ++ks)
#pragma unroll
      for (int td = 0; td < 4; ++td) {
        const short8 bv = *(const short8*)&Vs[cur][(td * 16 + l16) * 64 + (((ks * 4 + quad) ^ swz) << 3)];
        o[td] = __builtin_amdgcn_mfma_f32_16x16x32_bf16(bv, ap[ks], o[td], 0, 0, 0);
      }
  }

  // normalize + store ctx[b, gq, h*64 + d]; lane q = l16, d = td*16+quad*4+r
  const int b = bh >> 4, h = bh & 15;
  const float inv = 1.f / lsum;
  const int gq = q0 + w * 16 + l16;
  u16* crow = ctx + ((size_t)(b * 2048 + gq)) * 1024 + h * 64;
#pragma unroll
  for (int td = 0; td < 4; ++td) {
    unsigned int lo, hi;
    asm("v_cvt_pk_bf16_f32 %0, %1, %2"
        : "=v"(lo) : "v"(o[td][0] * inv), "v"(o[td][1] * inv));
    asm("v_cvt_pk_bf16_f32 %0, %1, %2"
        : "=v"(hi) : "v"(o[td][2] * inv), "v"(o[td][3] * inv));
    uint2v pk;
    pk.x = lo; pk.y = hi;
    *(uint2v*)(crow + td * 16 + quad * 4) = pk;
  }
}

// ---------------------------------------------------------------------------
extern "C" void kernel_launch(void* const* d_in, const int* in_sizes, int n_in,
                              void* d_out, int out_size, void* d_ws, size_t ws_size,
                              hipStream_t stream) {
  const float* x  = (const float*)d_in[0];
  // d_in[1] = attn_mask (causal tril) — implemented analytically
  const float* Wq = (const float*)d_in[2];
  const float* bq = (const float*)d_in[3];
  const float* Wk = (const float*)d_in[4];
  const float* bk = (const float*)d_in[5];
  const float* Wv = (const float*)d_in[6];
  const float* bv = (const float*)d_in[7];
  const float* Wo = (const float*)d_in[8];
  const float* bo = (const float*)d_in[9];

  u16* ws = (u16*)d_ws;
  const size_t WSZ = 1u << 20;   // 1024*1024
  const size_t TSZ = 8u << 20;   // 8192*1024
  u16* WqT = ws;                 // WqT|WkT|WvT contiguous = 3072x1024 Bt
  u16* WkT = ws + WSZ;
  u16* WvT = ws + 2 * WSZ;
  u16* WoT = ws + 3 * WSZ;
  u16* xb  = ws + 4 * WSZ;       // x bf16; dead after gemm_qkv -> reused as Vtb
  u16* Qb  = xb + TSZ;
  u16* Kb  = Qb + TSZ;
  u16* Vb  = Kb + TSZ;           // V [b,h,l,dh]; dead after transpose_v -> Ctx
  u16* Vtb = xb;
  u16* Ctx = Vb;

  const dim3 tb(256);
  cvt_x<<<dim3(4096), tb, 0, stream>>>(x, xb);
  transpose4<<<dim3(16, 16, 4), tb, 0, stream>>>(Wq, Wk, Wv, Wo, WqT, WkT, WvT, WoT);
  gemm_qkv<<<dim3(24, 64), tb, 0, stream>>>(xb, WqT, bq, bk, bv, Qb, Kb, Vb);
  transpose_v<<<dim3(32, 64), tb, 0, stream>>>(Vb, Vtb);
  attn_kernel<<<dim3(32, 64), tb, 0, stream>>>(Qb, Kb, Vtb, Ctx);
  gemm_out<<<dim3(8, 64), tb, 0, stream>>>(Ctx, WoT, bo, (float*)d_out, 8192, 1024, 1024);
}

// Round 2
// 299.484 us; speedup vs baseline: 1.3967x; 1.2021x over previous
//
#include <hip/hip_runtime.h>

// MHA forward. f32 in/out; bf16 MFMA compute (16x16x32), fp32 accum.
// Pipeline: cvt_x + transposeW -> merged QKV GEMM (all coalesced writes)
//           -> transpose_v -> flash attention (swapped-operand MFMA, lane-local
//           softmax, dbuf gll16 K/V, 1 barrier/iter) -> out GEMM.
// Workspace (u16): WqT,WkT,WvT(contig Bt),WoT (1M ea), xb(8M; ->Vtb),
// Qb, Kb, Vb(8M; ->Ctx) = 72 MB.
//
// R11 vs R10 (attn only):
// (1) Load balance: one block = q-tile pair (31-bx, bx) -> every block does
//     exactly 33 k-iters. Grid 16x64 = 1024 equal blocks = exactly 4/CU
//     co-resident (R10: 2048 blocks, 32x work spread, 18.7% occupancy).
// (2) P-store as ds_write_b64 (pairs k2=8tn+2quad+{0,1} adjacent): 4 word-
//     accesses/bank over a 4-cycle instr = zero conflict (R10's b32 pattern
//     hit 16 banks 4-way = 16 extra cyc/iter, matching the 2.16M counter).
// (3) Diag peel: unmasked main-loop iters + one masked final iter (-32 VALU
//     ops/iter on all non-diagonal tiles).

typedef unsigned short u16;
typedef __attribute__((ext_vector_type(8))) short short8;   // 8 bf16
typedef __attribute__((ext_vector_type(4))) float floatx4;  // 4 fp32
typedef __attribute__((ext_vector_type(2))) unsigned int uint2v;

#define NEG_BIG (-1e30f)
#define SCL_LOG2E 0.1803368801111244f  // (1/sqrt(64)) * log2(e)

__device__ __forceinline__ u16 f2bf(float f) {
  unsigned int u = __builtin_bit_cast(unsigned int, f);
  u += 0x7fffu + ((u >> 16) & 1u);
  return (u16)(u >> 16);
}

__device__ __forceinline__ short8 cvt8(const float* __restrict__ p) {
  const floatx4 a = *(const floatx4*)p;
  const floatx4 b = *(const floatx4*)(p + 4);
  short8 r;
  r[0] = (short)f2bf(a[0]); r[1] = (short)f2bf(a[1]);
  r[2] = (short)f2bf(a[2]); r[3] = (short)f2bf(a[3]);
  r[4] = (short)f2bf(b[0]); r[5] = (short)f2bf(b[1]);
  r[6] = (short)f2bf(b[2]); r[7] = (short)f2bf(b[3]);
  return r;
}

// async global->LDS, 16B/lane; LDS dest = wave-uniform base + lane*16 [m97]
__device__ __forceinline__ void gll16(const u16* g, u16* l) {
  __builtin_amdgcn_global_load_lds((const __attribute__((address_space(1))) void*)g,
                                   (__attribute__((address_space(3))) void*)l,
                                   16, 0, 0);
}

// ---------------------------------------------------------------------------
__global__ void cvt_x(const float* __restrict__ x, u16* __restrict__ xb) {
  const int i = blockIdx.x * 256 + threadIdx.x;  // 8 elems each
  *(short8*)(xb + (size_t)i * 8) = cvt8(x + (size_t)i * 8);
}

// ---------------------------------------------------------------------------
// 1024x1024 transpose + f32->bf16 (x4 matrices via grid.z).
__global__ void transpose4(const float* __restrict__ s0, const float* __restrict__ s1,
                           const float* __restrict__ s2, const float* __restrict__ s3,
                           u16* __restrict__ d0, u16* __restrict__ d1,
                           u16* __restrict__ d2, u16* __restrict__ d3) {
  __shared__ u16 tile[64][72];
  const float* src; u16* dst;
  switch (blockIdx.z) {
    case 0: src = s0; dst = d0; break;
    case 1: src = s1; dst = d1; break;
    case 2: src = s2; dst = d2; break;
    default: src = s3; dst = d3; break;
  }
  const int t = threadIdx.x;
  const int c = t & 63, rg = t >> 6;
  const int x0 = blockIdx.x * 64, y0 = blockIdx.y * 64;
#pragma unroll
  for (int i = 0; i < 16; ++i) {
    const int row = rg * 16 + i;
    tile[row][c] = f2bf(src[(size_t)(y0 + row) * 1024 + x0 + c]);
  }
  __syncthreads();
#pragma unroll
  for (int i = 0; i < 16; ++i) {
    const int row = rg * 16 + i;
    dst[(size_t)(x0 + row) * 1024 + y0 + c] = tile[c][row];
  }
}

// ---------------------------------------------------------------------------
// Per-head V transpose: Vb [b,h,l,dh] -> Vt [b,h,dh,l]. Coalesced both sides.
__global__ void transpose_v(const u16* __restrict__ Vb, u16* __restrict__ Vt) {
  __shared__ u16 tile[64][66];  // stride 66: column reads 2-way only
  const int bh = blockIdx.y;
  const int l0 = blockIdx.x * 64;
  const size_t base = (size_t)bh * (2048 * 64);
  const int t = threadIdx.x;
#pragma unroll
  for (int c = t; c < 512; c += 256) {
    const int row = c >> 3, cc = c & 7;
    *(short8*)&tile[row][cc * 8] =
        *(const short8*)(Vb + base + (size_t)(l0 + row) * 64 + cc * 8);
  }
  __syncthreads();
  const int c2 = t & 63, rg = t >> 6;
#pragma unroll
  for (int i = 0; i < 16; ++i) {
    const int dr = rg * 16 + i;
    Vt[base + (size_t)dr * 2048 + l0 + c2] = tile[c2][dr];
  }
}

// ---------------------------------------------------------------------------
// Merged QKV GEMM: A[8192,1024] bf16 @ Bt[3072,1024]^T (WqT|WkT|WvT) + bias.
// 128x128 tile, BK=32, m97 gll staging. All segs write [b,h,l,dh] (coalesced).
__global__ __launch_bounds__(256, 2) void gemm_qkv(
    const u16* __restrict__ A, const u16* __restrict__ Bt,
    const float* __restrict__ bq, const float* __restrict__ bk,
    const float* __restrict__ bv,
    u16* __restrict__ Qb, u16* __restrict__ Kb, u16* __restrict__ Vb) {
  const int K = 1024;
  __shared__ __align__(16) u16 As[128 * 32];
  __shared__ __align__(16) u16 Bs[128 * 32];
  const int t = threadIdx.x;
  const int w = t >> 6, l = t & 63;
  const int quad = l >> 4, l16 = l & 15;
  const int m0 = blockIdx.y * 128, n0 = blockIdx.x * 128;
  const int wr = w >> 1, wc = w & 1;

  floatx4 acc[4][4] = {};

  for (int k0 = 0; k0 < K; k0 += 32) {
    __syncthreads();
#pragma unroll
    for (int p = 0; p < 2; ++p) {
      const int c0 = (p * 4 + w) * 64;
      const int c = c0 + l;
      const int row = c >> 2;
      const int koff = (c & 3) * 8;
      gll16(A + (size_t)(m0 + row) * K + k0 + koff, &As[c0 * 8]);
      gll16(Bt + (size_t)(n0 + row) * K + k0 + koff, &Bs[c0 * 8]);
    }
    __syncthreads();

    short8 af[4], bf[4];
#pragma unroll
    for (int i = 0; i < 4; ++i)
      af[i] = *(const short8*)&As[(wr * 64 + i * 16 + l16) * 32 + quad * 8];
#pragma unroll
    for (int j = 0; j < 4; ++j)
      bf[j] = *(const short8*)&Bs[(wc * 64 + j * 16 + l16) * 32 + quad * 8];
#pragma unroll
    for (int i = 0; i < 4; ++i)
#pragma unroll
      for (int j = 0; j < 4; ++j)
        acc[i][j] = __builtin_amdgcn_mfma_f32_16x16x32_bf16(af[i], bf[j], acc[i][j], 0, 0, 0);
  }

  const int seg = n0 >> 10;  // 0=Q 1=K 2=V
  const float* bias = (seg == 0) ? bq : (seg == 1) ? bk : bv;
  u16* dst = (seg == 0) ? Qb : (seg == 1) ? Kb : Vb;
#pragma unroll
  for (int j = 0; j < 4; ++j) {
    const int nn = (n0 & 1023) + wc * 64 + j * 16 + l16;
    const float bvs = bias[nn];
    const int h = nn >> 6, dh = nn & 63;
#pragma unroll
    for (int i = 0; i < 4; ++i) {
      const int rb = m0 + wr * 64 + i * 16 + quad * 4;
#pragma unroll
      for (int r = 0; r < 4; ++r) {
        const int m = rb + r;
        const int b = m >> 11, ll = m & 2047;
        dst[((size_t)(b * 16 + h) * 2048 + ll) * 64 + dh] = f2bf(acc[i][j][r] + bvs);
      }
    }
  }
}

// ---------------------------------------------------------------------------
// Out GEMM: C[M,N] f32 = A[M,K] bf16 @ Bt[N,K]^T + bias[N].
__global__ __launch_bounds__(256, 2) void gemm_out(
    const u16* __restrict__ A, const u16* __restrict__ Bt,
    const float* __restrict__ bias, float* __restrict__ C, int M, int N, int K) {
  __shared__ __align__(16) u16 As[128 * 32];
  __shared__ __align__(16) u16 Bs[128 * 32];
  const int t = threadIdx.x;
  const int w = t >> 6, l = t & 63;
  const int quad = l >> 4, l16 = l & 15;
  const int m0 = blockIdx.y * 128, n0 = blockIdx.x * 128;
  const int wr = w >> 1, wc = w & 1;

  floatx4 acc[4][4] = {};

  for (int k0 = 0; k0 < K; k0 += 32) {
    __syncthreads();
#pragma unroll
    for (int p = 0; p < 2; ++p) {
      const int c0 = (p * 4 + w) * 64;
      const int c = c0 + l;
      const int row = c >> 2;
      const int koff = (c & 3) * 8;
      gll16(A + (size_t)(m0 + row) * K + k0 + koff, &As[c0 * 8]);
      gll16(Bt + (size_t)(n0 + row) * K + k0 + koff, &Bs[c0 * 8]);
    }
    __syncthreads();

    short8 af[4], bf[4];
#pragma unroll
    for (int i = 0; i < 4; ++i)
      af[i] = *(const short8*)&As[(wr * 64 + i * 16 + l16) * 32 + quad * 8];
#pragma unroll
    for (int j = 0; j < 4; ++j)
      bf[j] = *(const short8*)&Bs[(wc * 64 + j * 16 + l16) * 32 + quad * 8];
#pragma unroll
    for (int i = 0; i < 4; ++i)
#pragma unroll
      for (int j = 0; j < 4; ++j)
        acc[i][j] = __builtin_amdgcn_mfma_f32_16x16x32_bf16(af[i], bf[j], acc[i][j], 0, 0, 0);
  }

#pragma unroll
  for (int j = 0; j < 4; ++j) {
    const int n = n0 + wc * 64 + j * 16 + l16;
    const float bvs = bias[n];
#pragma unroll
    for (int i = 0; i < 4; ++i) {
      const int rb = m0 + wr * 64 + i * 16 + quad * 4;
#pragma unroll
      for (int r = 0; r < 4; ++r)
        C[(size_t)(rb + r) * N + n] = acc[i][j][r] + bvs;
    }
  }
}

// ---------------------------------------------------------------------------
// Flash attention, causal. Block = (pair bx, bh); each block runs TWO q-tiles
// (31-bx then bx) -> exactly 33 k-iters per block (perfect balance), grid
// 16x64 = 1024 equal blocks = 4/CU co-resident (LDS 40960 B).
// 4 waves x 16 q-rows, Q in regs. K/V 64x64 tiles double-buffered via gll16
// with chunk-XOR swizzle (stride 64, conflict-free b128 reads). ONE
// __syncthreads per k-tile (+1 between segments).
//
// Swapped-operand MFMA: s = mfma(K_frag, Q_frag) -> S^T: lane(quad,l16) holds
// S[k = tn*16+quad*4+r][q = l16]. Each lane owns ONE q-row: softmax max/sum
// are in-lane + shfl_xor(16)/shfl_xor(32); alpha/m/l once per lane.
// PV is o = mfma(Vt_frag, P_frag) -> O^T. P packed to bf16 pairs via
// v_cvt_pk_bf16_f32 and stored as 4x ds_write_b64 (zero-conflict: 4 word-
// accesses/bank over a 4-cycle instr) into wave-private swizzled LDS.
__global__ __launch_bounds__(256, 4) void attn_kernel(
    const u16* __restrict__ Q, const u16* __restrict__ K,
    const u16* __restrict__ Vt, u16* __restrict__ ctx) {
  __shared__ __align__(16) u16 Ks[2][64 * 64];
  __shared__ __align__(16) u16 Vs[2][64 * 64];
  __shared__ __align__(16) u16 Ps[4 * 16 * 64];

  const int t = threadIdx.x;
  const int w = t >> 6, l = t & 63;
  const int quad = l >> 4, l16 = l & 15;
  const int bh = blockIdx.y;
  const size_t base = (size_t)bh * (2048 * 64);
  u16* Pw = &Ps[w * 16 * 64];
  unsigned int* Pw32 = (unsigned int*)Pw;
  const int b = bh >> 4, h = bh & 15;

  // staging geometry: phys chunk pc = (p*4+w)*64 + l; logical row r = pc>>3,
  // chunk cl = (pc&7) ^ (r&7). gll16 dest = chunk-contiguous (lane*16).
  const int pc0 = w * 64 + l, pc1 = (4 + w) * 64 + l;
  const int sr0 = pc0 >> 3, sc0 = (pc0 & 7) ^ (sr0 & 7);
  const int sr1 = pc1 >> 3, sc1 = (pc1 & 7) ^ (sr1 & 7);
  const int swz = (l16 & 7);  // fragment-read chunk swizzle

  auto run_seg = [&](int q0, int nkt) {
    // Q fragments (lane's l16 = q-row): row = q0+w*16+l16, k = ks*32+quad*8
    short8 aq[2];
#pragma unroll
    for (int ks = 0; ks < 2; ++ks)
      aq[ks] = *(const short8*)(Q + base + (size_t)(q0 + w * 16 + l16) * 64 + ks * 32 + quad * 8);

    // prefetch tile 0 into buf 0
    gll16(K + base + (size_t)sr0 * 64 + sc0 * 8, &Ks[0][(w * 64) * 8]);
    gll16(K + base + (size_t)sr1 * 64 + sc1 * 8, &Ks[0][((4 + w) * 64) * 8]);
    gll16(Vt + base + (size_t)sr0 * 2048 + sc0 * 8, &Vs[0][(w * 64) * 8]);
    gll16(Vt + base + (size_t)sr1 * 2048 + sc1 * 8, &Vs[0][((4 + w) * 64) * 8]);

    floatx4 o[4] = {};
    float mrun = NEG_BIG, lsum = 0.f;

    auto body = [&](int kt, bool diag) {
      const int cur = kt & 1, nxt = cur ^ 1;
      __syncthreads();  // drains gll16s for buf[cur]; protects buf[nxt]
      if (!diag) {      // non-diag iters always have a next tile
        const int kn = (kt + 1) * 64;
        gll16(K + base + (size_t)(kn + sr0) * 64 + sc0 * 8, &Ks[nxt][(w * 64) * 8]);
        gll16(K + base + (size_t)(kn + sr1) * 64 + sc1 * 8, &Ks[nxt][((4 + w) * 64) * 8]);
        gll16(Vt + base + (size_t)sr0 * 2048 + kn + sc0 * 8, &Vs[nxt][(w * 64) * 8]);
        gll16(Vt + base + (size_t)sr1 * 2048 + kn + sc1 * 8, &Vs[nxt][((4 + w) * 64) * 8]);
      }

      // S^T = K Q^T : 8 MFMA (swapped operands); K frag row tn*16+l16
      floatx4 s[4] = {};
#pragma unroll
      for (int ks = 0; ks < 2; ++ks)
#pragma unroll
        for (int tn = 0; tn < 4; ++tn) {
          const short8 bk = *(const short8*)&Ks[cur][(tn * 16 + l16) * 64 + (((ks * 4 + quad) ^ swz) << 3)];
          s[tn] = __builtin_amdgcn_mfma_f32_16x16x32_bf16(bk, aq[ks], s[tn], 0, 0, 0);
        }

      // scale to log2 domain (+ causal mask, diag tile only) + in-lane max.
      // lane's k = tn*16 + quad*4 + r; lane's q (in-tile) = w*16 + l16.
      float mx = NEG_BIG;
#pragma unroll
      for (int tn = 0; tn < 4; ++tn)
#pragma unroll
        for (int r = 0; r < 4; ++r) {
          float v = s[tn][r] * SCL_LOG2E;
          if (diag && (tn * 16 + quad * 4 + r > w * 16 + l16)) v = NEG_BIG;
          s[tn][r] = v;
          mx = fmaxf(mx, v);
        }
      // cross-quad (same q lives in lanes l16, l16+16, l16+32, l16+48)
      mx = fmaxf(mx, __shfl_xor(mx, 16));
      mx = fmaxf(mx, __shfl_xor(mx, 32));

      const float mnew = fmaxf(mrun, mx);
      const float alpha = exp2f(mrun - mnew);
      mrun = mnew;
      float rs = 0.f;
#pragma unroll
      for (int tn = 0; tn < 4; ++tn)
#pragma unroll
        for (int r = 0; r < 4; ++r) {
          const float p = exp2f(s[tn][r] - mnew);
          s[tn][r] = p;
          rs += p;
        }
      rs += __shfl_xor(rs, 16);
      rs += __shfl_xor(rs, 32);
      lsum = lsum * alpha + rs;
#pragma unroll
      for (int td = 0; td < 4; ++td)
#pragma unroll
        for (int r = 0; r < 4; ++r) o[td][r] *= alpha;

      // P: pack k-pairs -> 2x u32 per tn, one ds_write_b64 each.
      // logical u32 word k2 = 8*tn + 2*quad + p; chunk c = 2*tn + (quad>>1);
      // swizzled chunk cc = c ^ (l16&7); intra-chunk offset 2*(quad&1)+p.
#pragma unroll
      for (int tn = 0; tn < 4; ++tn) {
        unsigned int p0, p1;
        asm("v_cvt_pk_bf16_f32 %0, %1, %2"
            : "=v"(p0) : "v"(s[tn][0]), "v"(s[tn][1]));
        asm("v_cvt_pk_bf16_f32 %0, %1, %2"
            : "=v"(p1) : "v"(s[tn][2]), "v"(s[tn][3]));
        const int cc = (2 * tn + (quad >> 1)) ^ swz;
        uint2v pr; pr.x = p0; pr.y = p1;
        *(uint2v*)&Pw32[l16 * 32 + cc * 4 + 2 * (quad & 1)] = pr;
      }
      __asm__ volatile("s_waitcnt lgkmcnt(0)" ::: "memory");
      __builtin_amdgcn_wave_barrier();

      // P fragment (B-operand): row l16 = q, k = ks*32+quad*8..+7 (de-swz)
      short8 ap[2];
#pragma unroll
      for (int ks = 0; ks < 2; ++ks)
        ap[ks] = *(const short8*)&Pw[l16 * 64 + (((ks * 4 + quad) ^ swz) << 3)];

      // O^T += V^T P^T : 8 MFMA (swapped); Vt frag row td*16+l16 (=dh)
#pragma unroll
      for (int ks = 0; ks < 2; ++ks)
#pragma unroll
        for (int td = 0; td < 4; ++td) {
          const short8 bv = *(const short8*)&Vs[cur][(td * 16 + l16) * 64 + (((ks * 4 + quad) ^ swz) << 3)];
          o[td] = __builtin_amdgcn_mfma_f32_16x16x32_bf16(bv, ap[ks], o[td], 0, 0, 0);
        }
    };

    for (int kt = 0; kt < nkt - 1; ++kt) body(kt, false);
    body(nkt - 1, true);

    // normalize + store ctx[b, gq, h*64 + d]; lane q = l16, d = td*16+quad*4+r
    const float inv = 1.f / lsum;
    const int gq = q0 + w * 16 + l16;
    u16* crow = ctx + ((size_t)(b * 2048 + gq)) * 1024 + h * 64;
#pragma unroll
    for (int td = 0; td < 4; ++td) {
      unsigned int lo, hi;
      asm("v_cvt_pk_bf16_f32 %0, %1, %2"
          : "=v"(lo) : "v"(o[td][0] * inv), "v"(o[td][1] * inv));
      asm("v_cvt_pk_bf16_f32 %0, %1, %2"
          : "=v"(hi) : "v"(o[td][2] * inv), "v"(o[td][3] * inv));
      uint2v pk;
      pk.x = lo; pk.y = hi;
      *(uint2v*)(crow + td * 16 + quad * 4) = pk;
    }
  };

  const int bx = blockIdx.x;          // 0..15
  run_seg((31 - bx) * 64, 32 - bx);   // heavy segment: nkt in [17,32]
  __syncthreads();                    // protect buf[0] before next prefetch
  run_seg(bx * 64, bx + 1);           // light segment: nkt in [1,16]
}

// ---------------------------------------------------------------------------
extern "C" void kernel_launch(void* const* d_in, const int* in_sizes, int n_in,
                              void* d_out, int out_size, void* d_ws, size_t ws_size,
                              hipStream_t stream) {
  const float* x  = (const float*)d_in[0];
  // d_in[1] = attn_mask (causal tril) — implemented analytically
  const float* Wq = (const float*)d_in[2];
  const float* bq = (const float*)d_in[3];
  const float* Wk = (const float*)d_in[4];
  const float* bk = (const float*)d_in[5];
  const float* Wv = (const float*)d_in[6];
  const float* bv = (const float*)d_in[7];
  const float* Wo = (const float*)d_in[8];
  const float* bo = (const float*)d_in[9];

  u16* ws = (u16*)d_ws;
  const size_t WSZ = 1u << 20;   // 1024*1024
  const size_t TSZ = 8u << 20;   // 8192*1024
  u16* WqT = ws;                 // WqT|WkT|WvT contiguous = 3072x1024 Bt
  u16* WkT = ws + WSZ;
  u16* WvT = ws + 2 * WSZ;
  u16* WoT = ws + 3 * WSZ;
  u16* xb  = ws + 4 * WSZ;       // x bf16; dead after gemm_qkv -> reused as Vtb
  u16* Qb  = xb + TSZ;
  u16* Kb  = Qb + TSZ;
  u16* Vb  = Kb + TSZ;           // V [b,h,l,dh]; dead after transpose_v -> Ctx
  u16* Vtb = xb;
  u16* Ctx = Vb;

  const dim3 tb(256);
  cvt_x<<<dim3(4096), tb, 0, stream>>>(x, xb);
  transpose4<<<dim3(16, 16, 4), tb, 0, stream>>>(Wq, Wk, Wv, Wo, WqT, WkT, WvT, WoT);
  gemm_qkv<<<dim3(24, 64), tb, 0, stream>>>(xb, WqT, bq, bk, bv, Qb, Kb, Vb);
  transpose_v<<<dim3(32, 64), tb, 0, stream>>>(Vb, Vtb);
  attn_kernel<<<dim3(16, 64), tb, 0, stream>>>(Qb, Kb, Vtb, Ctx);
  gemm_out<<<dim3(8, 64), tb, 0, stream>>>(Ctx, WoT, bo, (float*)d_out, 8192, 1024, 1024);
}